// Round 1
// baseline (275.595 us; speedup 1.0000x reference)
//
#include <hip/hip_runtime.h>
#include <hip/hip_bf16.h>
#include <cmath>

#define Bn 16
#define Nn 2048
#define Dn 1024
#define Hn 256
#define An 128

typedef __bf16 bf16x8 __attribute__((ext_vector_type(8)));
typedef float f32x4 __attribute__((ext_vector_type(4)));
typedef unsigned short ushort8v __attribute__((ext_vector_type(8)));

static __device__ __forceinline__ unsigned short f2bf(float f) {
  unsigned u = __float_as_uint(f);
  u += 0x7fffu + ((u >> 16) & 1u);   // round-to-nearest-even
  return (unsigned short)(u >> 16);
}

// ---------------- kernel 0: Wa1 fp32 -> bf16 ----------------
__global__ void conv_wa1_kernel(const float* __restrict__ w, unsigned short* __restrict__ o) {
  const int i = blockIdx.x * 256 + threadIdx.x;
  o[i] = f2bf(w[i]);
}

// ---------------- kernel 1: fused stage1 + stage2 ----------------
// grid: 16 * 32 blocks, 128 threads (2 waves). BM = 64 rows per block.
__global__ __launch_bounds__(128) void fused_main(
    const float* __restrict__ x,
    const float* __restrict__ W1,
    const float* __restrict__ b1,
    const float* __restrict__ ln_g,
    const float* __restrict__ ln_b,
    const float* __restrict__ ba1,
    const float* __restrict__ Wa2,
    const float* __restrict__ ba2,
    const float* __restrict__ Wc,
    const float* __restrict__ bc,
    const unsigned short* __restrict__ Wa1bf,
    float* __restrict__ scores_out,   // (B,N)
    float* __restrict__ logits_out)   // (B,N)
{
  // union: stage1 Ws[256][72] bf16 (36864B)  |  stage2 Hs[64][264] bf16 (33792B)
  __shared__ __align__(16) unsigned short smem[256 * 72];

  const int tid  = threadIdx.x;
  const int wv   = tid >> 6;        // wave 0..1
  const int lane = tid & 63;
  const int l15  = lane & 15;
  const int lhi  = lane >> 4;       // 0..3

  const int bb = blockIdx.x >> 5;
  const int n0 = (blockIdx.x & 31) << 6;   // *64

  f32x4 acc[2][16];
  #pragma unroll
  for (int rb = 0; rb < 2; ++rb)
    #pragma unroll
    for (int t = 0; t < 16; ++t)
      acc[rb][t] = (f32x4){0.f, 0.f, 0.f, 0.f};

  const float* xw = x + ((size_t)bb * Nn + n0 + wv * 32) * Dn;

  // ---------------- stage 1: h = x @ W1^T (MFMA, K=1024 in chunks of 64)
  for (int kc = 0; kc < 16; ++kc) {
    __syncthreads();
    {
      const int kq = (tid & 15) << 2;   // 0..60 step 4 (float4 along k)
      const int r0 = tid >> 4;          // 0..7
      #pragma unroll
      for (int p = 0; p < 32; ++p) {
        const int h = (p << 3) + r0;
        const float4 w4 = *(const float4*)(W1 + (size_t)h * Dn + (kc << 6) + kq);
        ushort4 pk;
        pk.x = f2bf(w4.x); pk.y = f2bf(w4.y); pk.z = f2bf(w4.z); pk.w = f2bf(w4.w);
        *(ushort4*)(smem + h * 72 + kq) = pk;
      }
    }
    __syncthreads();
    #pragma unroll
    for (int ks = 0; ks < 2; ++ks) {
      const int kk = (kc << 6) + (ks << 5) + (lhi << 3);
      bf16x8 af[2];
      #pragma unroll
      for (int rb = 0; rb < 2; ++rb) {
        const float* ap = xw + (size_t)((rb << 4) + l15) * Dn + kk;
        const float4 a0 = *(const float4*)ap;
        const float4 a1 = *(const float4*)(ap + 4);
        ushort8v u;
        u[0] = f2bf(a0.x); u[1] = f2bf(a0.y); u[2] = f2bf(a0.z); u[3] = f2bf(a0.w);
        u[4] = f2bf(a1.x); u[5] = f2bf(a1.y); u[6] = f2bf(a1.z); u[7] = f2bf(a1.w);
        af[rb] = __builtin_bit_cast(bf16x8, u);
      }
      #pragma unroll
      for (int t = 0; t < 16; ++t) {
        const bf16x8 bfg = *(const bf16x8*)(smem + ((t << 4) + l15) * 72 + (ks << 5) + (lhi << 3));
        acc[0][t] = __builtin_amdgcn_mfma_f32_16x16x32_bf16(af[0], bfg, acc[0][t], 0, 0, 0);
        acc[1][t] = __builtin_amdgcn_mfma_f32_16x16x32_bf16(af[1], bfg, acc[1][t], 0, 0, 0);
      }
    }
  }
  __syncthreads();   // Ws reads done; smem repurposed as Hs[64][264]

  const float bc0 = bc[0];
  // ---------------- epilogue 1: +b1, LayerNorm, GELU, score dot, pack Hs
  #pragma unroll
  for (int rb = 0; rb < 2; ++rb) {
    float ps[4] = {0, 0, 0, 0}, ps2[4] = {0, 0, 0, 0};
    #pragma unroll
    for (int t = 0; t < 16; ++t) {
      const float bv = b1[(t << 4) + l15];
      #pragma unroll
      for (int r = 0; r < 4; ++r) {
        const float v = acc[rb][t][r] + bv;
        acc[rb][t][r] = v;
        ps[r] += v; ps2[r] += v * v;
      }
    }
    #pragma unroll
    for (int r = 0; r < 4; ++r) {
      #pragma unroll
      for (int s = 1; s < 16; s <<= 1) {
        ps[r]  += __shfl_xor(ps[r],  s, 64);
        ps2[r] += __shfl_xor(ps2[r], s, 64);
      }
    }
    float mu[4], inv[4];
    #pragma unroll
    for (int r = 0; r < 4; ++r) {
      mu[r] = ps[r] * (1.f / 256.f);
      const float var = ps2[r] * (1.f / 256.f) - mu[r] * mu[r];
      inv[r] = rsqrtf(var + 1e-5f);
    }
    float sc[4] = {0, 0, 0, 0};
    const int rowb = (wv << 5) + (rb << 4);
    #pragma unroll
    for (int t = 0; t < 16; ++t) {
      const int col = (t << 4) + l15;
      const float gv = ln_g[col], bv2 = ln_b[col], wcv = Wc[col];
      #pragma unroll
      for (int r = 0; r < 4; ++r) {
        float v = (acc[rb][t][r] - mu[r]) * inv[r] * gv + bv2;
        v = 0.5f * v * (1.f + erff(v * 0.70710678118654752f));   // exact GELU
        sc[r] += v * wcv;
        smem[(rowb + (lhi << 2) + r) * 264 + col] = f2bf(v);
      }
    }
    #pragma unroll
    for (int r = 0; r < 4; ++r) {
      #pragma unroll
      for (int s = 1; s < 16; s <<= 1) sc[r] += __shfl_xor(sc[r], s, 64);
    }
    if (l15 == 0) {
      #pragma unroll
      for (int r = 0; r < 4; ++r)
        scores_out[(size_t)bb * Nn + n0 + rowb + (lhi << 2) + r] = sc[r] + bc0;
    }
  }
  __syncthreads();

  // ---------------- stage 2: a_hidden pre-act = Hs @ Wa1^T (M=64,K=256,N=128)
  f32x4 acc2[2][8];
  #pragma unroll
  for (int rb = 0; rb < 2; ++rb)
    #pragma unroll
    for (int t = 0; t < 8; ++t)
      acc2[rb][t] = (f32x4){0.f, 0.f, 0.f, 0.f};

  #pragma unroll
  for (int ks = 0; ks < 8; ++ks) {
    bf16x8 af[2];
    #pragma unroll
    for (int rb = 0; rb < 2; ++rb)
      af[rb] = *(const bf16x8*)(smem + ((wv << 5) + (rb << 4) + l15) * 264 + (ks << 5) + (lhi << 3));
    #pragma unroll
    for (int t = 0; t < 8; ++t) {
      const bf16x8 bfg = *(const bf16x8*)(Wa1bf + (size_t)((t << 4) + l15) * Hn + (ks << 5) + (lhi << 3));
      acc2[0][t] = __builtin_amdgcn_mfma_f32_16x16x32_bf16(af[0], bfg, acc2[0][t], 0, 0, 0);
      acc2[1][t] = __builtin_amdgcn_mfma_f32_16x16x32_bf16(af[1], bfg, acc2[1][t], 0, 0, 0);
    }
  }
  const float ba20 = ba2[0];
  #pragma unroll
  for (int rb = 0; rb < 2; ++rb) {
    float lg[4] = {0, 0, 0, 0};
    #pragma unroll
    for (int t = 0; t < 8; ++t) {
      const int col = (t << 4) + l15;
      const float bav = ba1[col], w2v = Wa2[col];
      #pragma unroll
      for (int r = 0; r < 4; ++r)
        lg[r] += tanhf(acc2[rb][t][r] + bav) * w2v;
    }
    #pragma unroll
    for (int r = 0; r < 4; ++r) {
      #pragma unroll
      for (int s = 1; s < 16; s <<= 1) lg[r] += __shfl_xor(lg[r], s, 64);
    }
    if (l15 == 0) {
      #pragma unroll
      for (int r = 0; r < 4; ++r)
        logits_out[(size_t)bb * Nn + n0 + (wv << 5) + (rb << 4) + (lhi << 2) + r] = lg[r] + ba20;
    }
  }
}

// ---------------- kernel 2: per-batch softmax pooling + dynamic top-k ----------------
__global__ __launch_bounds__(256) void finalize_kernel(
    const int* __restrict__ lengths,
    const float* __restrict__ scores,   // (B,N)
    const float* __restrict__ logits,   // (B,N)
    float* __restrict__ video)          // (B,)
{
  const int b = blockIdx.x;
  const int tid = threadIdx.x;
  __shared__ float sS[Nn];
  __shared__ float sL[Nn];
  __shared__ unsigned skey[Nn];
  __shared__ float sred[8];

  const int T = lengths[b];
  for (int i = tid; i < Nn; i += 256) {
    sS[i] = scores[(size_t)b * Nn + i];
    sL[i] = logits[(size_t)b * Nn + i];
  }
  __syncthreads();
  if (T <= 0) { if (tid == 0) video[b] = 0.f; return; }

  // max over valid logits
  float m = -3.0e38f;
  for (int i = tid; i < T; i += 256) m = fmaxf(m, sL[i]);
  #pragma unroll
  for (int s = 1; s < 64; s <<= 1) m = fmaxf(m, __shfl_xor(m, s, 64));
  if ((tid & 63) == 0) sred[tid >> 6] = m;
  __syncthreads();
  m = fmaxf(fmaxf(sred[0], sred[1]), fmaxf(sred[2], sred[3]));
  __syncthreads();

  // softmax denominator + weighted score sum (invalid terms are exactly 0)
  float se = 0.f, swe = 0.f;
  for (int i = tid; i < T; i += 256) {
    const float e = expf(sL[i] - m);
    se += e; swe += e * sS[i];
  }
  #pragma unroll
  for (int s = 1; s < 64; s <<= 1) { se += __shfl_xor(se, s, 64); swe += __shfl_xor(swe, s, 64); }
  if ((tid & 63) == 0) { sred[tid >> 6] = se; sred[4 + (tid >> 6)] = swe; }
  __syncthreads();
  se  = sred[0] + sred[1] + sred[2] + sred[3];
  swe = sred[4] + sred[5] + sred[6] + sred[7];
  __syncthreads();
  const float attn = swe / se;

  // monotonic uint keys for exact top-k threshold search
  for (int i = tid; i < T; i += 256) {
    const unsigned u = __float_as_uint(sS[i]);
    skey[i] = (u & 0x80000000u) ? ~u : (u | 0x80000000u);
  }
  __syncthreads();
  const int k = max(1, T / 10);
  unsigned ans = 0u;
  for (int bit = 31; bit >= 0; --bit) {
    const unsigned cand = ans | (1u << bit);
    int c = 0;
    for (int i = tid; i < T; i += 256) c += (skey[i] >= cand) ? 1 : 0;
    #pragma unroll
    for (int s = 1; s < 64; s <<= 1) c += __shfl_xor(c, s, 64);
    if ((tid & 63) == 0) sred[tid >> 6] = (float)c;
    __syncthreads();
    c = (int)(sred[0] + sred[1] + sred[2] + sred[3]);
    __syncthreads();
    if (c >= k) ans = cand;
  }
  // sum of strictly-greater + boundary multiplicity
  int cgt = 0; float sgt = 0.f;
  for (int i = tid; i < T; i += 256) {
    if (skey[i] > ans) { cgt++; sgt += sS[i]; }
  }
  #pragma unroll
  for (int s = 1; s < 64; s <<= 1) { cgt += __shfl_xor(cgt, s, 64); sgt += __shfl_xor(sgt, s, 64); }
  if ((tid & 63) == 0) { sred[tid >> 6] = (float)cgt; sred[4 + (tid >> 6)] = sgt; }
  __syncthreads();
  cgt = (int)(sred[0] + sred[1] + sred[2] + sred[3]);
  sgt = sred[4] + sred[5] + sred[6] + sred[7];

  const unsigned ub = (ans & 0x80000000u) ? (ans ^ 0x80000000u) : ~ans;
  const float kth = __uint_as_float(ub);
  const float topk = (sgt + (float)(k - cgt) * kth) / (float)k;
  if (tid == 0) video[b] = 0.5f * attn + 0.5f * topk;
}

extern "C" void kernel_launch(void* const* d_in, const int* in_sizes, int n_in,
                              void* d_out, int out_size, void* d_ws, size_t ws_size,
                              hipStream_t stream) {
  const float* x    = (const float*)d_in[0];
  const int*   len  = (const int*)  d_in[1];
  const float* W1   = (const float*)d_in[2];
  const float* b1   = (const float*)d_in[3];
  const float* ln_g = (const float*)d_in[4];
  const float* ln_b = (const float*)d_in[5];
  const float* Wa1  = (const float*)d_in[6];
  const float* ba1  = (const float*)d_in[7];
  const float* Wa2  = (const float*)d_in[8];
  const float* ba2  = (const float*)d_in[9];
  const float* Wc   = (const float*)d_in[10];
  const float* bc   = (const float*)d_in[11];

  float* out    = (float*)d_out;
  float* video  = out;          // (B,1) first
  float* scores = out + Bn;     // (B,N) second
  float* logits = (float*)d_ws;                                   // B*N f32
  unsigned short* wa1bf = (unsigned short*)((char*)d_ws + (size_t)Bn * Nn * sizeof(float));

  hipLaunchKernelGGL(conv_wa1_kernel, dim3((An * Hn) / 256), dim3(256), 0, stream, Wa1, wa1bf);
  hipLaunchKernelGGL(fused_main, dim3(Bn * (Nn / 64)), dim3(128), 0, stream,
                     x, W1, b1, ln_g, ln_b, ba1, Wa2, ba2, Wc, bc, wa1bf, scores, logits);
  hipLaunchKernelGGL(finalize_kernel, dim3(Bn), dim3(256), 0, stream, len, scores, logits, video);
}

// Round 2
// 198.185 us; speedup vs baseline: 1.3906x; 1.3906x over previous
//
#include <hip/hip_runtime.h>
#include <hip/hip_bf16.h>
#include <cmath>

#define Bn 16
#define Nn 2048
#define Dn 1024
#define Hn 256
#define An 128

typedef __bf16 bf16x8 __attribute__((ext_vector_type(8)));
typedef float f32x4 __attribute__((ext_vector_type(4)));
typedef unsigned short ushort8v __attribute__((ext_vector_type(8)));

static __device__ __forceinline__ unsigned short f2bf(float f) {
  unsigned u = __float_as_uint(f);
  u += 0x7fffu + ((u >> 16) & 1u);   // round-to-nearest-even
  return (unsigned short)(u >> 16);
}

static __device__ __forceinline__ bf16x8 cvt8(const float4 a, const float4 b) {
  bf16x8 r;
  r[0] = (__bf16)a.x; r[1] = (__bf16)a.y; r[2] = (__bf16)a.z; r[3] = (__bf16)a.w;
  r[4] = (__bf16)b.x; r[5] = (__bf16)b.y; r[6] = (__bf16)b.z; r[7] = (__bf16)b.w;
  return r;
}

// ---------------- kernel 0: fp32 -> bf16 weight conversion (8 elems/thread) --
__global__ void conv_bf16_kernel(const float* __restrict__ in, unsigned short* __restrict__ out) {
  const int i = (blockIdx.x * 256 + threadIdx.x) << 3;
  const float4 a = *(const float4*)(in + i);
  const float4 b = *(const float4*)(in + i + 4);
  ushort8v u;
  u[0] = f2bf(a.x); u[1] = f2bf(a.y); u[2] = f2bf(a.z); u[3] = f2bf(a.w);
  u[4] = f2bf(b.x); u[5] = f2bf(b.y); u[6] = f2bf(b.z); u[7] = f2bf(b.w);
  *(ushort8v*)(out + i) = u;
}

// ---------------- kernel 1: fused stage1 + stage2, barrier-free ----------------
// grid: 512 blocks x 256 threads (4 waves). Each wave owns 16 rows x 256 cols.
__global__ __launch_bounds__(256) void fused_main(
    const float* __restrict__ x,
    const float* __restrict__ b1,
    const float* __restrict__ ln_g,
    const float* __restrict__ ln_b,
    const float* __restrict__ ba1,
    const float* __restrict__ Wa2,
    const float* __restrict__ ba2,
    const float* __restrict__ Wc,
    const float* __restrict__ bc,
    const unsigned short* __restrict__ W1bf,   // (H=256, D=1024) bf16
    const unsigned short* __restrict__ Wa1bf,  // (A=128, H=256)  bf16
    float* __restrict__ scores_out,   // (B,N)
    float* __restrict__ logits_out)   // (B,N)
{
  // per-wave private h tile: [16 rows][264 cols] bf16  (264 pad -> 2-way banks)
  __shared__ __align__(16) __bf16 smem[4 * 16 * 264];

  const int tid  = threadIdx.x;
  const int wv   = tid >> 6;
  const int lane = tid & 63;
  const int l15  = lane & 15;
  const int lhi  = lane >> 4;       // 0..3

  const int gr0 = blockIdx.x * 64 + wv * 16;     // first global row of this wave
  const int bb  = gr0 >> 11;                     // batch
  const int nn  = gr0 & (Nn - 1);                // window index base

  __bf16* hreg = smem + wv * (16 * 264);

  f32x4 acc[16];
  #pragma unroll
  for (int t = 0; t < 16; ++t) acc[t] = (f32x4){0.f, 0.f, 0.f, 0.f};

  const float* xr = x + (size_t)(gr0 + l15) * Dn;
  const __bf16* wb = (const __bf16*)W1bf + l15 * Dn + (lhi << 3);

  // ---------------- stage 1: h = x @ W1^T  (M=16/wave, N=256, K=1024)
  #pragma unroll 2
  for (int kc = 0; kc < 32; ++kc) {
    const int kk = (kc << 5) + (lhi << 3);
    const float4 a0 = *(const float4*)(xr + kk);
    const float4 a1 = *(const float4*)(xr + kk + 4);
    const bf16x8 af = cvt8(a0, a1);
    const __bf16* wp = wb + (kc << 5);
    #pragma unroll
    for (int t = 0; t < 16; ++t) {
      const bf16x8 bfg = *(const bf16x8*)(wp + (t << 4) * Dn);
      acc[t] = __builtin_amdgcn_mfma_f32_16x16x32_bf16(af, bfg, acc[t], 0, 0, 0);
    }
  }

  // ---------------- epilogue 1: +b1, LayerNorm, GELU, score dot, pack h
  const float bc0 = bc[0];
  {
    float ps[4] = {0, 0, 0, 0}, ps2[4] = {0, 0, 0, 0};
    #pragma unroll
    for (int t = 0; t < 16; ++t) {
      const float bv = b1[(t << 4) + l15];
      #pragma unroll
      for (int r = 0; r < 4; ++r) {
        const float v = acc[t][r] + bv;
        acc[t][r] = v;
        ps[r] += v; ps2[r] += v * v;
      }
    }
    #pragma unroll
    for (int r = 0; r < 4; ++r) {
      #pragma unroll
      for (int s = 1; s < 16; s <<= 1) {
        ps[r]  += __shfl_xor(ps[r],  s, 64);
        ps2[r] += __shfl_xor(ps2[r], s, 64);
      }
    }
    float mu[4], inv[4];
    #pragma unroll
    for (int r = 0; r < 4; ++r) {
      mu[r] = ps[r] * (1.f / 256.f);
      const float var = ps2[r] * (1.f / 256.f) - mu[r] * mu[r];
      inv[r] = rsqrtf(var + 1e-5f);
    }
    float sc[4] = {0, 0, 0, 0};
    #pragma unroll
    for (int t = 0; t < 16; ++t) {
      const int col = (t << 4) + l15;
      const float gv = ln_g[col], bv2 = ln_b[col], wcv = Wc[col];
      #pragma unroll
      for (int r = 0; r < 4; ++r) {
        float v = (acc[t][r] - mu[r]) * inv[r] * gv + bv2;
        v = 0.5f * v * (1.f + erff(v * 0.70710678118654752f));   // exact GELU
        sc[r] += v * wcv;
        hreg[((lhi << 2) + r) * 264 + col] = (__bf16)v;
      }
    }
    #pragma unroll
    for (int r = 0; r < 4; ++r) {
      #pragma unroll
      for (int s = 1; s < 16; s <<= 1) sc[r] += __shfl_xor(sc[r], s, 64);
    }
    if (l15 == 0) {
      #pragma unroll
      for (int r = 0; r < 4; ++r)
        scores_out[(size_t)bb * Nn + nn + (lhi << 2) + r] = sc[r] + bc0;
    }
  }

  // ---------------- stage 2: pre-act = h @ Wa1^T  (M=16, K=256, N=128)
  f32x4 acc2[8];
  #pragma unroll
  for (int t = 0; t < 8; ++t) acc2[t] = (f32x4){0.f, 0.f, 0.f, 0.f};

  const __bf16* wab = (const __bf16*)Wa1bf + l15 * Hn + (lhi << 3);
  #pragma unroll
  for (int ks = 0; ks < 8; ++ks) {
    const bf16x8 af = *(const bf16x8*)(hreg + l15 * 264 + (ks << 5) + (lhi << 3));
    #pragma unroll
    for (int t = 0; t < 8; ++t) {
      const bf16x8 bfg = *(const bf16x8*)(wab + (t << 4) * Hn + (ks << 5));
      acc2[t] = __builtin_amdgcn_mfma_f32_16x16x32_bf16(af, bfg, acc2[t], 0, 0, 0);
    }
  }
  const float ba20 = ba2[0];
  {
    float lg[4] = {0, 0, 0, 0};
    #pragma unroll
    for (int t = 0; t < 8; ++t) {
      const int col = (t << 4) + l15;
      const float bav = ba1[col], w2v = Wa2[col];
      #pragma unroll
      for (int r = 0; r < 4; ++r)
        lg[r] += tanhf(acc2[t][r] + bav) * w2v;
    }
    #pragma unroll
    for (int r = 0; r < 4; ++r) {
      #pragma unroll
      for (int s = 1; s < 16; s <<= 1) lg[r] += __shfl_xor(lg[r], s, 64);
    }
    if (l15 == 0) {
      #pragma unroll
      for (int r = 0; r < 4; ++r)
        logits_out[(size_t)bb * Nn + nn + (lhi << 2) + r] = lg[r] + ba20;
    }
  }
}

// ---------------- kernel 2: per-batch softmax pooling + dynamic top-k --------
__global__ __launch_bounds__(256) void finalize_kernel(
    const int* __restrict__ lengths,
    const float* __restrict__ scores,   // (B,N)
    const float* __restrict__ logits,   // (B,N)
    float* __restrict__ video)          // (B,)
{
  const int b = blockIdx.x;
  const int tid = threadIdx.x;
  __shared__ float sS[Nn];
  __shared__ float sL[Nn];
  __shared__ unsigned skey[Nn];
  __shared__ float sred[8];

  const int T = lengths[b];
  for (int i = tid; i < Nn; i += 256) {
    sS[i] = scores[(size_t)b * Nn + i];
    sL[i] = logits[(size_t)b * Nn + i];
  }
  __syncthreads();
  if (T <= 0) { if (tid == 0) video[b] = 0.f; return; }

  float m = -3.0e38f;
  for (int i = tid; i < T; i += 256) m = fmaxf(m, sL[i]);
  #pragma unroll
  for (int s = 1; s < 64; s <<= 1) m = fmaxf(m, __shfl_xor(m, s, 64));
  if ((tid & 63) == 0) sred[tid >> 6] = m;
  __syncthreads();
  m = fmaxf(fmaxf(sred[0], sred[1]), fmaxf(sred[2], sred[3]));
  __syncthreads();

  float se = 0.f, swe = 0.f;
  for (int i = tid; i < T; i += 256) {
    const float e = expf(sL[i] - m);
    se += e; swe += e * sS[i];
  }
  #pragma unroll
  for (int s = 1; s < 64; s <<= 1) { se += __shfl_xor(se, s, 64); swe += __shfl_xor(swe, s, 64); }
  if ((tid & 63) == 0) { sred[tid >> 6] = se; sred[4 + (tid >> 6)] = swe; }
  __syncthreads();
  se  = sred[0] + sred[1] + sred[2] + sred[3];
  swe = sred[4] + sred[5] + sred[6] + sred[7];
  __syncthreads();
  const float attn = swe / se;

  for (int i = tid; i < T; i += 256) {
    const unsigned u = __float_as_uint(sS[i]);
    skey[i] = (u & 0x80000000u) ? ~u : (u | 0x80000000u);
  }
  __syncthreads();
  const int k = max(1, T / 10);
  unsigned ans = 0u;
  for (int bit = 31; bit >= 0; --bit) {
    const unsigned cand = ans | (1u << bit);
    int c = 0;
    for (int i = tid; i < T; i += 256) c += (skey[i] >= cand) ? 1 : 0;
    #pragma unroll
    for (int s = 1; s < 64; s <<= 1) c += __shfl_xor(c, s, 64);
    if ((tid & 63) == 0) sred[tid >> 6] = (float)c;
    __syncthreads();
    c = (int)(sred[0] + sred[1] + sred[2] + sred[3]);
    __syncthreads();
    if (c >= k) ans = cand;
  }
  int cgt = 0; float sgt = 0.f;
  for (int i = tid; i < T; i += 256) {
    if (skey[i] > ans) { cgt++; sgt += sS[i]; }
  }
  #pragma unroll
  for (int s = 1; s < 64; s <<= 1) { cgt += __shfl_xor(cgt, s, 64); sgt += __shfl_xor(sgt, s, 64); }
  if ((tid & 63) == 0) { sred[tid >> 6] = (float)cgt; sred[4 + (tid >> 6)] = sgt; }
  __syncthreads();
  cgt = (int)(sred[0] + sred[1] + sred[2] + sred[3]);
  sgt = sred[4] + sred[5] + sred[6] + sred[7];

  const unsigned ub = (ans & 0x80000000u) ? (ans ^ 0x80000000u) : ~ans;
  const float kth = __uint_as_float(ub);
  const float topk = (sgt + (float)(k - cgt) * kth) / (float)k;
  if (tid == 0) video[b] = 0.5f * attn + 0.5f * topk;
}

extern "C" void kernel_launch(void* const* d_in, const int* in_sizes, int n_in,
                              void* d_out, int out_size, void* d_ws, size_t ws_size,
                              hipStream_t stream) {
  const float* x    = (const float*)d_in[0];
  const int*   len  = (const int*)  d_in[1];
  const float* W1   = (const float*)d_in[2];
  const float* b1   = (const float*)d_in[3];
  const float* ln_g = (const float*)d_in[4];
  const float* ln_b = (const float*)d_in[5];
  const float* Wa1  = (const float*)d_in[6];
  const float* ba1  = (const float*)d_in[7];
  const float* Wa2  = (const float*)d_in[8];
  const float* ba2  = (const float*)d_in[9];
  const float* Wc   = (const float*)d_in[10];
  const float* bc   = (const float*)d_in[11];

  float* out    = (float*)d_out;
  float* video  = out;          // (B,1) first
  float* scores = out + Bn;     // (B,N) second

  char* ws = (char*)d_ws;
  float*          logits = (float*)ws;                                  // B*N f32
  unsigned short* wa1bf  = (unsigned short*)(ws + (size_t)Bn * Nn * 4); // 64 KB
  unsigned short* w1bf   = (unsigned short*)(ws + (size_t)Bn * Nn * 4 + (size_t)An * Hn * 2);

  hipLaunchKernelGGL(conv_bf16_kernel, dim3((Hn * Dn) / 2048), dim3(256), 0, stream, W1, w1bf);
  hipLaunchKernelGGL(conv_bf16_kernel, dim3((An * Hn) / 2048), dim3(256), 0, stream, Wa1, wa1bf);
  hipLaunchKernelGGL(fused_main, dim3(Bn * Nn / 64), dim3(256), 0, stream,
                     x, b1, ln_g, ln_b, ba1, Wa2, ba2, Wc, bc,
                     w1bf, wa1bf, scores, logits);
  hipLaunchKernelGGL(finalize_kernel, dim3(Bn), dim3(256), 0, stream, len, scores, logits, video);
}

// Round 3
// 95.693 us; speedup vs baseline: 2.8800x; 2.0710x over previous
//
#include <hip/hip_runtime.h>
#include <hip/hip_bf16.h>
#include <cmath>

#define Bn 16
#define Nn 2048
#define Dn 1024
#define Hn 256
#define An 128

typedef __bf16 bf16x8 __attribute__((ext_vector_type(8)));
typedef float f32x4 __attribute__((ext_vector_type(4)));
typedef unsigned short ushort8v __attribute__((ext_vector_type(8)));

static __device__ __forceinline__ unsigned short f2bf(float f) {
  unsigned u = __float_as_uint(f);
  u += 0x7fffu + ((u >> 16) & 1u);   // round-to-nearest-even
  return (unsigned short)(u >> 16);
}

static __device__ __forceinline__ bf16x8 cvt8(const float4 a, const float4 b) {
  bf16x8 r;
  r[0] = (__bf16)a.x; r[1] = (__bf16)a.y; r[2] = (__bf16)a.z; r[3] = (__bf16)a.w;
  r[4] = (__bf16)b.x; r[5] = (__bf16)b.y; r[6] = (__bf16)b.z; r[7] = (__bf16)b.w;
  return r;
}

static __device__ __forceinline__ void glds16(const void* g, void* l) {
  __builtin_amdgcn_global_load_lds(
      (const __attribute__((address_space(1))) unsigned int*)g,
      (__attribute__((address_space(3))) unsigned int*)l, 16, 0, 0);
}

// ---------------- kernel 0: weight fp32 -> bf16 (W1 then Wa1) ----------------
__global__ __launch_bounds__(256) void conv_bf16_kernel(
    const float* __restrict__ W1, const float* __restrict__ Wa1,
    unsigned short* __restrict__ w1o, unsigned short* __restrict__ wa1o) {
  const int bid = blockIdx.x;
  const float* in;
  unsigned short* out;
  int i;
  if (bid < 128) { in = W1;  out = w1o;  i = (bid * 256 + threadIdx.x) << 3; }
  else           { in = Wa1; out = wa1o; i = ((bid - 128) * 256 + threadIdx.x) << 3; }
  const float4 a = *(const float4*)(in + i);
  const float4 b = *(const float4*)(in + i + 4);
  ushort8v u;
  u[0] = f2bf(a.x); u[1] = f2bf(a.y); u[2] = f2bf(a.z); u[3] = f2bf(a.w);
  u[4] = f2bf(b.x); u[5] = f2bf(b.y); u[6] = f2bf(b.z); u[7] = f2bf(b.w);
  *(ushort8v*)(out + i) = u;
}

// ---------------- kernel 1: fused stage1 (LDS-tiled GEMM) + LN/GELU + stage2 --
// grid 512 blocks x 256 threads (4 waves). BM=64 rows, BN=256 (full H), BK=32.
// wave tile 32 rows x 128 cols: wv = rg*2 + cw.
__global__ __launch_bounds__(256) void fused_main(
    const float* __restrict__ x,
    const float* __restrict__ b1,
    const float* __restrict__ ln_g,
    const float* __restrict__ ln_b,
    const float* __restrict__ ba1,
    const float* __restrict__ Wa2,
    const float* __restrict__ ba2,
    const float* __restrict__ Wc,
    const float* __restrict__ bc,
    const unsigned short* __restrict__ W1bf,   // (256,1024) bf16
    const unsigned short* __restrict__ Wa1bf,  // (128,256)  bf16
    float* __restrict__ scores_out,
    float* __restrict__ logits_out)
{
  // A dbuf: 2 x 64x32 bf16 (8KB) | B dbuf: 2 x 256x32 bf16 (32KB); h reuses [0,32KB)
  __shared__ __align__(16) __bf16 AB[4096 + 16384];
  __shared__ float red[64][8];

  const int tid  = threadIdx.x;
  const int wv   = tid >> 6;
  const int lane = tid & 63;
  const int l15  = lane & 15;
  const int lhi  = lane >> 4;
  const int rg   = wv >> 1;         // row group (0..1): rows rg*32..+32
  const int cw   = wv & 1;          // col wave (0..1): cols cw*128..+128

  const int gr0 = blockIdx.x << 6;            // first global row (B*N flat)
  const int bb  = blockIdx.x >> 5;
  const int n0  = (blockIdx.x & 31) << 6;

  char* ABb = (char*)AB;

  f32x4 acc[2][8];
  #pragma unroll
  for (int rf = 0; rf < 2; ++rf)
    #pragma unroll
    for (int cf = 0; cf < 8; ++cf)
      acc[rf][cf] = (f32x4){0.f, 0.f, 0.f, 0.f};

  // staging geometry (per thread / per wave)
  const int st_row   = tid >> 2;                         // A: row 0..63
  const int st_lslot = (tid & 3) ^ ((tid >> 3) & 3);     // A: logical 16B slot
  const float* xbase = x + (size_t)(gr0 + st_row) * Dn + (st_lslot << 3);

  // B glds: 4 chunks per wave; chunk c = wv*256 + i*64 + lane
  // issue loads for step kc into buffer p
  auto issueB = [&](int p, int kc) {
    const int kk = kc << 5;
    char* Bb = ABb + 8192 + p * 16384;
    #pragma unroll
    for (int i = 0; i < 4; ++i) {
      const int c = (wv << 8) + (i << 6) + lane;
      const int h = c >> 2;
      const int lslot = (c & 3) ^ ((c >> 3) & 3);
      glds16(W1bf + (size_t)h * Dn + kk + (lslot << 3),
             ABb + 8192 + p * 16384 + ((wv << 8) + (i << 6)) * 16);
      (void)Bb;
    }
  };

  auto computeStep = [&](int p) {
    const char* Ab = ABb + p * 4096;
    const char* Bb = ABb + 8192 + p * 16384;
    bf16x8 afrag[2];
    #pragma unroll
    for (int rf = 0; rf < 2; ++rf) {
      const int row = (rg << 5) + (rf << 4) + l15;
      afrag[rf] = *(const bf16x8*)(Ab + row * 64 + ((lhi ^ ((row >> 1) & 3)) << 4));
    }
    #pragma unroll
    for (int cf = 0; cf < 8; ++cf) {
      const int h = (cw << 7) + (cf << 4) + l15;
      const bf16x8 bfr = *(const bf16x8*)(Bb + h * 64 + ((lhi ^ ((h >> 1) & 3)) << 4));
      acc[0][cf] = __builtin_amdgcn_mfma_f32_16x16x32_bf16(afrag[0], bfr, acc[0][cf], 0, 0, 0);
      acc[1][cf] = __builtin_amdgcn_mfma_f32_16x16x32_bf16(afrag[1], bfr, acc[1][cf], 0, 0, 0);
    }
  };

  // ---------------- prologue: stage k-step 0 into buffer 0
  {
    issueB(0, 0);
    const float4 a0 = *(const float4*)(xbase);
    const float4 a1 = *(const float4*)(xbase + 4);
    *(bf16x8*)(ABb + (tid << 4)) = cvt8(a0, a1);
  }
  __syncthreads();

  int p = 0;
  for (int kc = 0; kc < 32; ++kc) {
    const int np = p ^ 1;
    float4 na0, na1;
    if (kc < 31) {
      issueB(np, kc + 1);
      const float* xs = xbase + ((kc + 1) << 5);
      na0 = *(const float4*)(xs);
      na1 = *(const float4*)(xs + 4);
    }
    computeStep(p);
    if (kc < 31)
      *(bf16x8*)(ABb + np * 4096 + (tid << 4)) = cvt8(na0, na1);
    __syncthreads();
    p = np;
  }

  // ---------------- epilogue 1: +b1, LayerNorm (cross-wave), GELU, Wc dot, pack h
  const float bc0 = bc[0];
  float b1v[8];
  #pragma unroll
  for (int cf = 0; cf < 8; ++cf) b1v[cf] = b1[(cw << 7) + (cf << 4) + l15];

  float ps[2][4], ps2[2][4];
  #pragma unroll
  for (int rf = 0; rf < 2; ++rf)
    #pragma unroll
    for (int r = 0; r < 4; ++r) { ps[rf][r] = 0.f; ps2[rf][r] = 0.f; }

  #pragma unroll
  for (int rf = 0; rf < 2; ++rf)
    #pragma unroll
    for (int cf = 0; cf < 8; ++cf)
      #pragma unroll
      for (int r = 0; r < 4; ++r) {
        const float v = acc[rf][cf][r] + b1v[cf];
        acc[rf][cf][r] = v;
        ps[rf][r] += v; ps2[rf][r] += v * v;
      }
  #pragma unroll
  for (int rf = 0; rf < 2; ++rf)
    #pragma unroll
    for (int r = 0; r < 4; ++r)
      #pragma unroll
      for (int s = 1; s < 16; s <<= 1) {
        ps[rf][r]  += __shfl_xor(ps[rf][r],  s, 64);
        ps2[rf][r] += __shfl_xor(ps2[rf][r], s, 64);
      }
  if (l15 == 0) {
    #pragma unroll
    for (int rf = 0; rf < 2; ++rf)
      #pragma unroll
      for (int r = 0; r < 4; ++r) {
        const int rowb = (rg << 5) + (rf << 4) + (lhi << 2) + r;
        red[rowb][cw << 1]       = ps[rf][r];
        red[rowb][(cw << 1) + 1] = ps2[rf][r];
      }
  }
  __syncthreads();

  float mu[2][4], inv[2][4];
  #pragma unroll
  for (int rf = 0; rf < 2; ++rf)
    #pragma unroll
    for (int r = 0; r < 4; ++r) {
      const int rowb = (rg << 5) + (rf << 4) + (lhi << 2) + r;
      const float s = red[rowb][0] + red[rowb][2];
      const float q = red[rowb][1] + red[rowb][3];
      const float m = s * (1.f / 256.f);
      const float var = q * (1.f / 256.f) - m * m;
      mu[rf][r] = m;
      inv[rf][r] = rsqrtf(var + 1e-5f);
    }

  float gv[8], bv[8], wcv[8];
  #pragma unroll
  for (int cf = 0; cf < 8; ++cf) {
    const int col = (cw << 7) + (cf << 4) + l15;
    gv[cf] = ln_g[col]; bv[cf] = ln_b[col]; wcv[cf] = Wc[col];
  }
  float sc[2][4];
  #pragma unroll
  for (int rf = 0; rf < 2; ++rf)
    #pragma unroll
    for (int r = 0; r < 4; ++r) sc[rf][r] = 0.f;

  #pragma unroll
  for (int rf = 0; rf < 2; ++rf)
    #pragma unroll
    for (int cf = 0; cf < 8; ++cf)
      #pragma unroll
      for (int r = 0; r < 4; ++r) {
        float v = (acc[rf][cf][r] - mu[rf][r]) * inv[rf][r] * gv[cf] + bv[cf];
        v = 0.5f * v * (1.f + erff(v * 0.70710678118654752f));   // exact GELU
        sc[rf][r] += v * wcv[cf];
        const int rowb = (rg << 5) + (rf << 4) + (lhi << 2) + r;
        const int col  = (cw << 7) + (cf << 4) + l15;
        *(__bf16*)(ABb + rowb * 512 + (((col >> 3) ^ (rowb & 7)) << 4) + ((col & 7) << 1)) = (__bf16)v;
      }
  #pragma unroll
  for (int rf = 0; rf < 2; ++rf)
    #pragma unroll
    for (int r = 0; r < 4; ++r)
      #pragma unroll
      for (int s = 1; s < 16; s <<= 1)
        sc[rf][r] += __shfl_xor(sc[rf][r], s, 64);
  if (l15 == 0) {
    #pragma unroll
    for (int rf = 0; rf < 2; ++rf)
      #pragma unroll
      for (int r = 0; r < 4; ++r) {
        const int rowb = (rg << 5) + (rf << 4) + (lhi << 2) + r;
        red[rowb][4 + cw] = sc[rf][r];
      }
  }
  __syncthreads();
  if (tid < 64)
    scores_out[(size_t)bb * Nn + n0 + tid] = red[tid][4] + red[tid][5] + bc0;

  // ---------------- stage 2: pre-act = h @ Wa1^T (per wave: 16 rows, K=256, N=128)
  f32x4 acc2[8];
  #pragma unroll
  for (int cf = 0; cf < 8; ++cf) acc2[cf] = (f32x4){0.f, 0.f, 0.f, 0.f};

  const int r16 = (wv << 4) + l15;
  #pragma unroll
  for (int ks = 0; ks < 8; ++ks) {
    const bf16x8 af = *(const bf16x8*)(ABb + r16 * 512 + ((((ks << 2) + lhi) ^ (r16 & 7)) << 4));
    #pragma unroll
    for (int cf = 0; cf < 8; ++cf) {
      const bf16x8 bfr = *(const bf16x8*)((const __bf16*)Wa1bf +
                          (size_t)((cf << 4) + l15) * Hn + (ks << 5) + (lhi << 3));
      acc2[cf] = __builtin_amdgcn_mfma_f32_16x16x32_bf16(af, bfr, acc2[cf], 0, 0, 0);
    }
  }
  const float ba20 = ba2[0];
  float lg[4] = {0.f, 0.f, 0.f, 0.f};
  #pragma unroll
  for (int cf = 0; cf < 8; ++cf) {
    const int col = (cf << 4) + l15;
    const float bav = ba1[col], w2v = Wa2[col];
    #pragma unroll
    for (int r = 0; r < 4; ++r) {
      const float t = acc2[cf][r] + bav;
      const float e = __expf(2.f * t);
      const float th = 1.f - 2.f / (e + 1.f);
      lg[r] += th * w2v;
    }
  }
  #pragma unroll
  for (int r = 0; r < 4; ++r)
    #pragma unroll
    for (int s = 1; s < 16; s <<= 1) lg[r] += __shfl_xor(lg[r], s, 64);
  if (l15 == 0) {
    #pragma unroll
    for (int r = 0; r < 4; ++r)
      logits_out[(size_t)bb * Nn + n0 + (wv << 4) + (lhi << 2) + r] = lg[r] + ba20;
  }
}

// ---------------- kernel 2: per-batch softmax pooling + dynamic top-k --------
__global__ __launch_bounds__(256) void finalize_kernel(
    const int* __restrict__ lengths,
    const float* __restrict__ scores,
    const float* __restrict__ logits,
    float* __restrict__ video)
{
  const int b = blockIdx.x;
  const int tid = threadIdx.x;
  __shared__ float sS[Nn];
  __shared__ float sL[Nn];
  __shared__ unsigned skey[Nn];
  __shared__ float sred[8];

  const int T = lengths[b];
  for (int i = tid; i < Nn; i += 256) {
    sS[i] = scores[(size_t)b * Nn + i];
    sL[i] = logits[(size_t)b * Nn + i];
  }
  __syncthreads();
  if (T <= 0) { if (tid == 0) video[b] = 0.f; return; }

  float m = -3.0e38f;
  for (int i = tid; i < T; i += 256) m = fmaxf(m, sL[i]);
  #pragma unroll
  for (int s = 1; s < 64; s <<= 1) m = fmaxf(m, __shfl_xor(m, s, 64));
  if ((tid & 63) == 0) sred[tid >> 6] = m;
  __syncthreads();
  m = fmaxf(fmaxf(sred[0], sred[1]), fmaxf(sred[2], sred[3]));
  __syncthreads();

  float se = 0.f, swe = 0.f;
  for (int i = tid; i < T; i += 256) {
    const float e = expf(sL[i] - m);
    se += e; swe += e * sS[i];
  }
  #pragma unroll
  for (int s = 1; s < 64; s <<= 1) { se += __shfl_xor(se, s, 64); swe += __shfl_xor(swe, s, 64); }
  if ((tid & 63) == 0) { sred[tid >> 6] = se; sred[4 + (tid >> 6)] = swe; }
  __syncthreads();
  se  = sred[0] + sred[1] + sred[2] + sred[3];
  swe = sred[4] + sred[5] + sred[6] + sred[7];
  __syncthreads();
  const float attn = swe / se;

  for (int i = tid; i < T; i += 256) {
    const unsigned u = __float_as_uint(sS[i]);
    skey[i] = (u & 0x80000000u) ? ~u : (u | 0x80000000u);
  }
  __syncthreads();
  const int k = max(1, T / 10);
  unsigned ans = 0u;
  for (int bit = 31; bit >= 0; --bit) {
    const unsigned cand = ans | (1u << bit);
    int c = 0;
    for (int i = tid; i < T; i += 256) c += (skey[i] >= cand) ? 1 : 0;
    #pragma unroll
    for (int s = 1; s < 64; s <<= 1) c += __shfl_xor(c, s, 64);
    if ((tid & 63) == 0) sred[tid >> 6] = (float)c;
    __syncthreads();
    c = (int)(sred[0] + sred[1] + sred[2] + sred[3]);
    __syncthreads();
    if (c >= k) ans = cand;
  }
  int cgt = 0; float sgt = 0.f;
  for (int i = tid; i < T; i += 256) {
    if (skey[i] > ans) { cgt++; sgt += sS[i]; }
  }
  #pragma unroll
  for (int s = 1; s < 64; s <<= 1) { cgt += __shfl_xor(cgt, s, 64); sgt += __shfl_xor(sgt, s, 64); }
  if ((tid & 63) == 0) { sred[tid >> 6] = (float)cgt; sred[4 + (tid >> 6)] = sgt; }
  __syncthreads();
  cgt = (int)(sred[0] + sred[1] + sred[2] + sred[3]);
  sgt = sred[4] + sred[5] + sred[6] + sred[7];

  const unsigned ub = (ans & 0x80000000u) ? (ans ^ 0x80000000u) : ~ans;
  const float kth = __uint_as_float(ub);
  const float topk = (sgt + (float)(k - cgt) * kth) / (float)k;
  if (tid == 0) video[b] = 0.5f * attn + 0.5f * topk;
}

extern "C" void kernel_launch(void* const* d_in, const int* in_sizes, int n_in,
                              void* d_out, int out_size, void* d_ws, size_t ws_size,
                              hipStream_t stream) {
  const float* x    = (const float*)d_in[0];
  const int*   len  = (const int*)  d_in[1];
  const float* W1   = (const float*)d_in[2];
  const float* b1   = (const float*)d_in[3];
  const float* ln_g = (const float*)d_in[4];
  const float* ln_b = (const float*)d_in[5];
  const float* Wa1  = (const float*)d_in[6];
  const float* ba1  = (const float*)d_in[7];
  const float* Wa2  = (const float*)d_in[8];
  const float* ba2  = (const float*)d_in[9];
  const float* Wc   = (const float*)d_in[10];
  const float* bc   = (const float*)d_in[11];

  float* out    = (float*)d_out;
  float* video  = out;
  float* scores = out + Bn;

  char* ws = (char*)d_ws;
  float*          logits = (float*)ws;                                   // 128KB
  unsigned short* wa1bf  = (unsigned short*)(ws + (size_t)Bn * Nn * 4);  // 64KB
  unsigned short* w1bf   = (unsigned short*)(ws + (size_t)Bn * Nn * 4 + (size_t)An * Hn * 2);

  hipLaunchKernelGGL(conv_bf16_kernel, dim3(144), dim3(256), 0, stream, W1, Wa1, w1bf, wa1bf);
  hipLaunchKernelGGL(fused_main, dim3(Bn * Nn / 64), dim3(256), 0, stream,
                     x, b1, ln_g, ln_b, ba1, Wa2, ba2, Wc, bc,
                     w1bf, wa1bf, scores, logits);
  hipLaunchKernelGGL(finalize_kernel, dim3(Bn), dim3(256), 0, stream, len, scores, logits, video);
}

// Round 5
// 88.900 us; speedup vs baseline: 3.1001x; 1.0764x over previous
//
#include <hip/hip_runtime.h>
#include <hip/hip_bf16.h>
#include <cmath>

#define Bn 16
#define Nn 2048
#define Dn 1024
#define Hn 256
#define An 128

typedef __bf16 bf16x8 __attribute__((ext_vector_type(8)));
typedef float f32x4 __attribute__((ext_vector_type(4)));
typedef unsigned short ushort8v __attribute__((ext_vector_type(8)));

// LDS layout (80 KB exactly, 2 blocks/CU):
//   A0 [0,8K)   A1 [8K,16K)    each 64 rows x 128B (64 bf16 k, 16B-slot XOR swizzle)
//   B0 [16K,48K) B1 [48K,80K)  each 256 rows x 128B
//   epilogue aliases: red (64x8 f32) at 8K (A1 dead), h tile 64x512B at 48K (B1 dead)
#define LDSA(p) ((p) * 8192)
#define LDSB(p) (16384 + (p) * 32768)
#define LDSH    49152
#define LDSRED  8192

#define PIPE_BARRIER(N) do {                                        \
    asm volatile("s_waitcnt vmcnt(" #N ") lgkmcnt(0)" ::: "memory"); \
    __builtin_amdgcn_s_barrier();                                   \
    __builtin_amdgcn_sched_barrier(0);                              \
  } while (0)

static __device__ __forceinline__ unsigned short f2bf(float f) {
  unsigned u = __float_as_uint(f);
  u += 0x7fffu + ((u >> 16) & 1u);
  return (unsigned short)(u >> 16);
}

static __device__ __forceinline__ bf16x8 cvt8(const float4 a, const float4 b) {
  bf16x8 r;
  r[0] = (__bf16)a.x; r[1] = (__bf16)a.y; r[2] = (__bf16)a.z; r[3] = (__bf16)a.w;
  r[4] = (__bf16)b.x; r[5] = (__bf16)b.y; r[6] = (__bf16)b.z; r[7] = (__bf16)b.w;
  return r;
}

static __device__ __forceinline__ void glds16(const void* g, void* l) {
  __builtin_amdgcn_global_load_lds(
      (const __attribute__((address_space(1))) unsigned int*)g,
      (__attribute__((address_space(3))) unsigned int*)l, 16, 0, 0);
}

// ---------------- kernel 0: weight fp32 -> bf16 (W1 then Wa1) ----------------
__global__ __launch_bounds__(256) void conv_bf16_kernel(
    const float* __restrict__ W1, const float* __restrict__ Wa1,
    unsigned short* __restrict__ w1o, unsigned short* __restrict__ wa1o) {
  const int bid = blockIdx.x;
  const float* in;
  unsigned short* out;
  int i;
  if (bid < 128) { in = W1;  out = w1o;  i = (bid * 256 + threadIdx.x) << 3; }
  else           { in = Wa1; out = wa1o; i = ((bid - 128) * 256 + threadIdx.x) << 3; }
  const float4 a = *(const float4*)(in + i);
  const float4 b = *(const float4*)(in + i + 4);
  ushort8v u;
  u[0] = f2bf(a.x); u[1] = f2bf(a.y); u[2] = f2bf(a.z); u[3] = f2bf(a.w);
  u[4] = f2bf(b.x); u[5] = f2bf(b.y); u[6] = f2bf(b.z); u[7] = f2bf(b.w);
  *(ushort8v*)(out + i) = u;
}

// ---------------- kernel 1: fused stage1 GEMM (pipelined) + LN/GELU + stage2 --
// grid 512 x 256 thr (4 waves). BM=64, BN=256, BK=64, 16 k-steps.
// wave tile 32 rows x 128 cols: wv = rg*2 + cw.
__global__ __launch_bounds__(256) void fused_main(
    const float* __restrict__ x,
    const float* __restrict__ b1,
    const float* __restrict__ ln_g,
    const float* __restrict__ ln_b,
    const float* __restrict__ ba1,
    const float* __restrict__ Wa2,
    const float* __restrict__ ba2,
    const float* __restrict__ Wc,
    const float* __restrict__ bc,
    const unsigned short* __restrict__ W1bf,   // (256,1024) bf16
    const unsigned short* __restrict__ Wa1bf,  // (128,256)  bf16
    float* __restrict__ scores_out,
    float* __restrict__ logits_out)
{
  __shared__ __align__(16) char lds[81920];

  const int tid  = threadIdx.x;
  const int wv   = tid >> 6;
  const int lane = tid & 63;
  const int l15  = lane & 15;
  const int lhi  = lane >> 4;
  const int rg   = wv >> 1;
  const int cw   = wv & 1;

  const int gr0 = blockIdx.x << 6;
  const int bb  = blockIdx.x >> 5;
  const int n0  = (blockIdx.x & 31) << 6;

  f32x4 acc[2][8];
  #pragma unroll
  for (int rf = 0; rf < 2; ++rf)
    #pragma unroll
    for (int cf = 0; cf < 8; ++cf)
      acc[rf][cf] = (f32x4){0.f, 0.f, 0.f, 0.f};

  // A staging: thread -> row tid>>2, k-quarter tid&3 (16 k's = 2 swizzled 16B slots)
  const int arow = tid >> 2;
  const int aq   = tid & 3;
  const float* xbase = x + (size_t)(gr0 + arow) * Dn + (aq << 4);
  char* awr0 = lds + arow * 128 + (((aq << 1)       ^ (arow & 7)) << 4);
  char* awr1 = lds + arow * 128 + ((((aq << 1) | 1) ^ (arow & 7)) << 4);

  // B staging via glds: wave wv covers rows wv*64 + i*8 (i=0..7), 1KB per chunk.
  // source pre-swizzled so linear LDS dest yields phys slot s = logical ^ (h&7).
  const unsigned short* bsrc = W1bf + (size_t)(wv * 64 + (lane >> 3)) * Dn
                               + (((lane & 7) ^ ((lane >> 3) & 7)) << 3);

  const int axor = l15 & 7;   // (row&7) for ALL frag rows (A, B, h)

  auto issueB = [&](int p, int kc) {
    #pragma unroll
    for (int i = 0; i < 8; ++i)
      glds16(bsrc + (size_t)i * 8 * Dn + (kc << 6),
             lds + LDSB(p) + (wv * 64 + i * 8) * 128);
  };
  auto loadX = [&](float4* v, int kc) {
    #pragma unroll
    for (int j = 0; j < 4; ++j)
      v[j] = *(const float4*)(xbase + (kc << 6) + (j << 2));
  };
  auto writeA = [&](int p, const float4* v) {
    *(bf16x8*)(awr0 + LDSA(p)) = cvt8(v[0], v[1]);
    *(bf16x8*)(awr1 + LDSA(p)) = cvt8(v[2], v[3]);
  };
  auto computeStep = [&](int p) {
    const char* Ab = lds + LDSA(p);
    const char* Bb = lds + LDSB(p);
    #pragma unroll
    for (int ks = 0; ks < 2; ++ks) {
      const int so = (((ks << 2) + lhi) ^ axor) << 4;
      const bf16x8 aA = *(const bf16x8*)(Ab + ((rg << 5) + l15) * 128 + so);
      const bf16x8 aB = *(const bf16x8*)(Ab + ((rg << 5) + 16 + l15) * 128 + so);
      #pragma unroll
      for (int cf = 0; cf < 8; ++cf) {
        const bf16x8 bfr = *(const bf16x8*)(Bb + ((cw << 7) + (cf << 4) + l15) * 128 + so);
        acc[0][cf] = __builtin_amdgcn_mfma_f32_16x16x32_bf16(aA, bfr, acc[0][cf], 0, 0, 0);
        acc[1][cf] = __builtin_amdgcn_mfma_f32_16x16x32_bf16(aB, bfr, acc[1][cf], 0, 0, 0);
      }
    }
  };

  // -------- prologue: B(0) glds, x(0)->A0, x(1) in regs
  // sched_barrier(0) pins VMEM issue order: glds FIRST, then x-loads — the
  // counted vmcnt below is only valid if the glds are the oldest in flight.
  float4 xr0[4], xr1[4];
  issueB(0, 0);
  __builtin_amdgcn_sched_barrier(0);
  loadX(xr0, 0);
  loadX(xr1, 1);
  __builtin_amdgcn_sched_barrier(0);
  writeA(0, xr0);           // auto-waits x(0); glds(0) drains with it
  PIPE_BARRIER(4);          // x(1) stays in flight

  // -------- main loop, fully unrolled: waits are literal constants
  #pragma unroll
  for (int kc = 0; kc < 16; ++kc) {
    const int p = kc & 1;
    const int np = p ^ 1;
    if (kc < 15) issueB(np, kc + 1);                    // 8 glds (oldest this step)
    __builtin_amdgcn_sched_barrier(0);
    if (kc < 14) loadX((kc & 1) ? xr1 : xr0, kc + 2);   // 4 x-loads (newest)
    __builtin_amdgcn_sched_barrier(0);
    computeStep(p);                                      // 20 ds_read + 32 MFMA
    if (kc < 15) {
      writeA(np, np ? xr1 : xr0);                        // x(kc+1), loaded 1 step ago
      if (kc < 14) PIPE_BARRIER(4);                      // glds done, x(kc+2) in flight
      else         PIPE_BARRIER(0);                      // tail: drain all
    }
  }
  __syncthreads();   // LDS repurpose: h at LDSH (B1), red at LDSRED (A1)

  float (*red)[8] = (float(*)[8])(lds + LDSRED);

  // ---------------- epilogue 1: +b1, LayerNorm (cross-wave), GELU, Wc dot, pack h
  const float bc0 = bc[0];
  float b1v[8];
  #pragma unroll
  for (int cf = 0; cf < 8; ++cf) b1v[cf] = b1[(cw << 7) + (cf << 4) + l15];

  float ps[2][4], ps2[2][4];
  #pragma unroll
  for (int rf = 0; rf < 2; ++rf)
    #pragma unroll
    for (int r = 0; r < 4; ++r) { ps[rf][r] = 0.f; ps2[rf][r] = 0.f; }

  #pragma unroll
  for (int rf = 0; rf < 2; ++rf)
    #pragma unroll
    for (int cf = 0; cf < 8; ++cf)
      #pragma unroll
      for (int r = 0; r < 4; ++r) {
        const float v = acc[rf][cf][r] + b1v[cf];
        acc[rf][cf][r] = v;
        ps[rf][r] += v; ps2[rf][r] += v * v;
      }
  #pragma unroll
  for (int rf = 0; rf < 2; ++rf)
    #pragma unroll
    for (int r = 0; r < 4; ++r)
      #pragma unroll
      for (int s = 1; s < 16; s <<= 1) {
        ps[rf][r]  += __shfl_xor(ps[rf][r],  s, 64);
        ps2[rf][r] += __shfl_xor(ps2[rf][r], s, 64);
      }
  if (l15 == 0) {
    #pragma unroll
    for (int rf = 0; rf < 2; ++rf)
      #pragma unroll
      for (int r = 0; r < 4; ++r) {
        const int rowb = (rg << 5) + (rf << 4) + (lhi << 2) + r;
        red[rowb][cw << 1]       = ps[rf][r];
        red[rowb][(cw << 1) + 1] = ps2[rf][r];
      }
  }
  __syncthreads();

  float mu[2][4], inv[2][4];
  #pragma unroll
  for (int rf = 0; rf < 2; ++rf)
    #pragma unroll
    for (int r = 0; r < 4; ++r) {
      const int rowb = (rg << 5) + (rf << 4) + (lhi << 2) + r;
      const float s = red[rowb][0] + red[rowb][2];
      const float q = red[rowb][1] + red[rowb][3];
      const float m = s * (1.f / 256.f);
      const float var = q * (1.f / 256.f) - m * m;
      mu[rf][r] = m;
      inv[rf][r] = rsqrtf(var + 1e-5f);
    }

  float gv[8], bv[8], wcv[8];
  #pragma unroll
  for (int cf = 0; cf < 8; ++cf) {
    const int col = (cw << 7) + (cf << 4) + l15;
    gv[cf] = ln_g[col]; bv[cf] = ln_b[col]; wcv[cf] = Wc[col];
  }
  float sc[2][4];
  #pragma unroll
  for (int rf = 0; rf < 2; ++rf)
    #pragma unroll
    for (int r = 0; r < 4; ++r) sc[rf][r] = 0.f;

  #pragma unroll
  for (int rf = 0; rf < 2; ++rf)
    #pragma unroll
    for (int cf = 0; cf < 8; ++cf)
      #pragma unroll
      for (int r = 0; r < 4; ++r) {
        float v = (acc[rf][cf][r] - mu[rf][r]) * inv[rf][r] * gv[cf] + bv[cf];
        v = 0.5f * v * (1.f + erff(v * 0.70710678118654752f));   // exact GELU
        sc[rf][r] += v * wcv[cf];
        const int rowb = (rg << 5) + (rf << 4) + (lhi << 2) + r;
        const int col  = (cw << 7) + (cf << 4) + l15;
        *(__bf16*)(lds + LDSH + rowb * 512 + (((col >> 3) ^ (rowb & 7)) << 4)
                   + ((col & 7) << 1)) = (__bf16)v;
      }
  #pragma unroll
  for (int rf = 0; rf < 2; ++rf)
    #pragma unroll
    for (int r = 0; r < 4; ++r)
      #pragma unroll
      for (int s = 1; s < 16; s <<= 1)
        sc[rf][r] += __shfl_xor(sc[rf][r], s, 64);
  if (l15 == 0) {
    #pragma unroll
    for (int rf = 0; rf < 2; ++rf)
      #pragma unroll
      for (int r = 0; r < 4; ++r) {
        const int rowb = (rg << 5) + (rf << 4) + (lhi << 2) + r;
        red[rowb][4 + cw] = sc[rf][r];
      }
  }
  __syncthreads();
  if (tid < 64)
    scores_out[(size_t)bb * Nn + n0 + tid] = red[tid][4] + red[tid][5] + bc0;

  // ---------------- stage 2: pre-act = h @ Wa1^T (per wave: 16 rows, K=256, N=128)
  f32x4 acc2[8];
  #pragma unroll
  for (int cf = 0; cf < 8; ++cf) acc2[cf] = (f32x4){0.f, 0.f, 0.f, 0.f};

  const int r16 = (wv << 4) + l15;
  #pragma unroll
  for (int ks = 0; ks < 8; ++ks) {
    const bf16x8 af = *(const bf16x8*)(lds + LDSH + r16 * 512 +
                        ((((ks << 2) + lhi) ^ (r16 & 7)) << 4));
    #pragma unroll
    for (int cf = 0; cf < 8; ++cf) {
      const bf16x8 bfr = *(const bf16x8*)((const __bf16*)Wa1bf +
                          (size_t)((cf << 4) + l15) * Hn + (ks << 5) + (lhi << 3));
      acc2[cf] = __builtin_amdgcn_mfma_f32_16x16x32_bf16(af, bfr, acc2[cf], 0, 0, 0);
    }
  }
  const float ba20 = ba2[0];
  float lg[4] = {0.f, 0.f, 0.f, 0.f};
  #pragma unroll
  for (int cf = 0; cf < 8; ++cf) {
    const int col = (cf << 4) + l15;
    const float bav = ba1[col], w2v = Wa2[col];
    #pragma unroll
    for (int r = 0; r < 4; ++r) {
      const float t = acc2[cf][r] + bav;
      const float e = __expf(2.f * t);
      const float th = 1.f - 2.f / (e + 1.f);
      lg[r] += th * w2v;
    }
  }
  #pragma unroll
  for (int r = 0; r < 4; ++r)
    #pragma unroll
    for (int s = 1; s < 16; s <<= 1) lg[r] += __shfl_xor(lg[r], s, 64);
  if (l15 == 0) {
    #pragma unroll
    for (int r = 0; r < 4; ++r)
      logits_out[(size_t)bb * Nn + n0 + (wv << 4) + (lhi << 2) + r] = lg[r] + ba20;
  }
}

// ---------------- kernel 2: per-batch softmax pooling + dynamic top-k --------
__global__ __launch_bounds__(256) void finalize_kernel(
    const int* __restrict__ lengths,
    const float* __restrict__ scores,
    const float* __restrict__ logits,
    float* __restrict__ video)
{
  const int b = blockIdx.x;
  const int tid = threadIdx.x;
  __shared__ float sS[Nn];
  __shared__ float sL[Nn];
  __shared__ unsigned skey[Nn];
  __shared__ float sred[8];

  const int T = lengths[b];
  for (int i = tid; i < Nn; i += 256) {
    sS[i] = scores[(size_t)b * Nn + i];
    sL[i] = logits[(size_t)b * Nn + i];
  }
  __syncthreads();
  if (T <= 0) { if (tid == 0) video[b] = 0.f; return; }

  float m = -3.0e38f;
  for (int i = tid; i < T; i += 256) m = fmaxf(m, sL[i]);
  #pragma unroll
  for (int s = 1; s < 64; s <<= 1) m = fmaxf(m, __shfl_xor(m, s, 64));
  if ((tid & 63) == 0) sred[tid >> 6] = m;
  __syncthreads();
  m = fmaxf(fmaxf(sred[0], sred[1]), fmaxf(sred[2], sred[3]));
  __syncthreads();

  float se = 0.f, swe = 0.f;
  for (int i = tid; i < T; i += 256) {
    const float e = expf(sL[i] - m);
    se += e; swe += e * sS[i];
  }
  #pragma unroll
  for (int s = 1; s < 64; s <<= 1) { se += __shfl_xor(se, s, 64); swe += __shfl_xor(swe, s, 64); }
  if ((tid & 63) == 0) { sred[tid >> 6] = se; sred[4 + (tid >> 6)] = swe; }
  __syncthreads();
  se  = sred[0] + sred[1] + sred[2] + sred[3];
  swe = sred[4] + sred[5] + sred[6] + sred[7];
  __syncthreads();
  const float attn = swe / se;

  for (int i = tid; i < T; i += 256) {
    const unsigned u = __float_as_uint(sS[i]);
    skey[i] = (u & 0x80000000u) ? ~u : (u | 0x80000000u);
  }
  __syncthreads();
  const int k = max(1, T / 10);
  unsigned ans = 0u;
  for (int bit = 31; bit >= 0; --bit) {
    const unsigned cand = ans | (1u << bit);
    int c = 0;
    for (int i = tid; i < T; i += 256) c += (skey[i] >= cand) ? 1 : 0;
    #pragma unroll
    for (int s = 1; s < 64; s <<= 1) c += __shfl_xor(c, s, 64);
    if ((tid & 63) == 0) sred[tid >> 6] = (float)c;
    __syncthreads();
    c = (int)(sred[0] + sred[1] + sred[2] + sred[3]);
    __syncthreads();
    if (c >= k) ans = cand;
  }
  int cgt = 0; float sgt = 0.f;
  for (int i = tid; i < T; i += 256) {
    if (skey[i] > ans) { cgt++; sgt += sS[i]; }
  }
  #pragma unroll
  for (int s = 1; s < 64; s <<= 1) { cgt += __shfl_xor(cgt, s, 64); sgt += __shfl_xor(sgt, s, 64); }
  if ((tid & 63) == 0) { sred[tid >> 6] = (float)cgt; sred[4 + (tid >> 6)] = sgt; }
  __syncthreads();
  cgt = (int)(sred[0] + sred[1] + sred[2] + sred[3]);
  sgt = sred[4] + sred[5] + sred[6] + sred[7];

  const unsigned ub = (ans & 0x80000000u) ? (ans ^ 0x80000000u) : ~ans;
  const float kth = __uint_as_float(ub);
  const float topk = (sgt + (float)(k - cgt) * kth) / (float)k;
  if (tid == 0) video[b] = 0.5f * attn + 0.5f * topk;
}

extern "C" void kernel_launch(void* const* d_in, const int* in_sizes, int n_in,
                              void* d_out, int out_size, void* d_ws, size_t ws_size,
                              hipStream_t stream) {
  const float* x    = (const float*)d_in[0];
  const int*   len  = (const int*)  d_in[1];
  const float* W1   = (const float*)d_in[2];
  const float* b1   = (const float*)d_in[3];
  const float* ln_g = (const float*)d_in[4];
  const float* ln_b = (const float*)d_in[5];
  const float* Wa1  = (const float*)d_in[6];
  const float* ba1  = (const float*)d_in[7];
  const float* Wa2  = (const float*)d_in[8];
  const float* ba2  = (const float*)d_in[9];
  const float* Wc   = (const float*)d_in[10];
  const float* bc   = (const float*)d_in[11];

  float* out    = (float*)d_out;
  float* video  = out;
  float* scores = out + Bn;

  char* ws = (char*)d_ws;
  float*          logits = (float*)ws;                                   // 128KB
  unsigned short* wa1bf  = (unsigned short*)(ws + (size_t)Bn * Nn * 4);  // 64KB
  unsigned short* w1bf   = (unsigned short*)(ws + (size_t)Bn * Nn * 4 + (size_t)An * Hn * 2);

  hipLaunchKernelGGL(conv_bf16_kernel, dim3(144), dim3(256), 0, stream, W1, Wa1, w1bf, wa1bf);
  hipLaunchKernelGGL(fused_main, dim3(Bn * Nn / 64), dim3(256), 0, stream,
                     x, b1, ln_g, ln_b, ba1, Wa2, ba2, Wc, bc,
                     w1bf, wa1bf, scores, logits);
  hipLaunchKernelGGL(finalize_kernel, dim3(Bn), dim3(256), 0, stream, len, scores, logits, video);
}